// Round 5
// baseline (934.430 us; speedup 1.0000x reference)
//
#include <hip/hip_runtime.h>

// ---------------------------------------------------------------------------
// meta_model: out = (w0*sig(Ll Ll^T) + w1*sig((La La^T)*aa) + w2*sig((Lm Lm^T)*mod)
//                    - sig(Lu Lu^T)) * adj + sig(Lu Lu^T)
// with L* = mlp(feat), w = softmax(ws)
//
// R4: k_ctx restructured as a row-strip sweeper (R1-R3 were latency-bound;
// compiler waitcnt is in-order, so register-prefetch across MFMA phases is
// structurally defeated - VGPR_Count 64/84/124 proved repeated sinking):
//   - wave = 16 rows x 2048-col strip (128 steps of 16x16 tiles)
//   - A-frags for ALL 4 latents (64 VGPR) loaded ONCE per sweep
//   - per step: 16 fj loads (L2-resident panel), 3 nontemporal ew float4
//     (HBM), 16 MFMA, fused sigmoid combine, 1 float4 store
//   - steps independent -> unroll 2 = natural pipeline; 8 waves/CU;
//     ~48KB/CU in flight >> 9KB needed for 6.3 TB/s
//   - 512 blocks = 128 rowgroups x 4 colstrips; round-robin XCD placement
//     gives each XCD one colstrip -> 2MB fj panel L2-hot
// ---------------------------------------------------------------------------

typedef __attribute__((ext_vector_type(8))) short short8;
typedef __attribute__((ext_vector_type(4))) float f32x4;

__device__ __forceinline__ unsigned short f2bf(float x) {
  union { float f; unsigned u; } v; v.f = x;
  unsigned u = v.u + 0x7FFFu + ((v.u >> 16) & 1u);   // round-to-nearest-even
  return (unsigned short)(u >> 16);
}

__device__ __forceinline__ float sigf(float x) {
  float e = __builtin_amdgcn_exp2f(-1.4426950408889634f * x);
  return __builtin_amdgcn_rcpf(1.0f + e);
}

// --------------------------- stage A0: feat -> frag -------------------------
__global__ __launch_bounds__(256) void k_featfrag(const float* __restrict__ feat,
                                                  unsigned short* __restrict__ dst) {
  int t = blockIdx.x * 256 + threadIdx.x;   // 8192 rows * 64 chunks
  int row = t >> 6, kc = t & 63;            // 8 cols per thread
  const float4* s = reinterpret_cast<const float4*>(feat + row * 512 + kc * 8);
  float4 v0 = s[0], v1 = s[1];
  short8 o;
  o[0] = f2bf(v0.x); o[1] = f2bf(v0.y); o[2] = f2bf(v0.z); o[3] = f2bf(v0.w);
  o[4] = f2bf(v1.x); o[5] = f2bf(v1.y); o[6] = f2bf(v1.z); o[7] = f2bf(v1.w);
  int mb = row >> 4, kk = kc >> 2;
  int lane = ((kc & 3) << 4) | (row & 15);
  *reinterpret_cast<short8*>(dst + ((size_t)((mb * 16 + kk) * 64 + lane)) * 8) = o;
}

// --------------------- stage A0w: W1/W2 -> B-frag layout ---------------------
__global__ __launch_bounds__(256) void k_wfrag(
    const float* __restrict__ w1_0, const float* __restrict__ w1_1,
    const float* __restrict__ w1_2, const float* __restrict__ w1_3,
    const float* __restrict__ w2_0, const float* __restrict__ w2_1,
    const float* __restrict__ w2_2, const float* __restrict__ w2_3,
    unsigned short* __restrict__ w1f, unsigned short* __restrict__ w2f) {
  int t = blockIdx.x * 256 + threadIdx.x;
  if (t < 32768) {  // W1frag: [g][kk=16][nb=8][lane=64][j=8]
    int lane = t & 63, nb = (t >> 6) & 7, kk = (t >> 9) & 15, g = t >> 13;
    const float* W = g == 0 ? w1_0 : g == 1 ? w1_1 : g == 2 ? w1_2 : w1_3;
    int q = lane >> 4, r = lane & 15;
    int col = nb * 16 + r;
    short8 o;
#pragma unroll
    for (int j = 0; j < 8; ++j) o[j] = f2bf(W[(kk * 32 + q * 8 + j) * 128 + col]);
    *reinterpret_cast<short8*>(w1f + (size_t)t * 8) = o;
  } else if (t < 40960) {  // W2frag: [g][kk=4][nb=8][lane=64][j=8]
    int t2 = t - 32768;
    int lane = t2 & 63, nb = (t2 >> 6) & 7, kk = (t2 >> 9) & 3, g = t2 >> 11;
    const float* W = g == 0 ? w2_0 : g == 1 ? w2_1 : g == 2 ? w2_2 : w2_3;
    int q = lane >> 4, r = lane & 15;
    int col = nb * 16 + r;
    short8 o;
#pragma unroll
    for (int j = 0; j < 8; ++j) o[j] = f2bf(W[(kk * 32 + q * 8 + j) * 128 + col]);
    *reinterpret_cast<short8*>(w2f + (size_t)t2 * 8) = o;
  }
}

// --------------------- stage A1: H = relu(feat@W1cat + b1) -------------------
__global__ __launch_bounds__(256) void k_gemm1(
    const unsigned short* __restrict__ featf, const unsigned short* __restrict__ w1f,
    const float* __restrict__ b1_0, const float* __restrict__ b1_1,
    const float* __restrict__ b1_2, const float* __restrict__ b1_3,
    unsigned short* __restrict__ hfrag) {
  int bi = blockIdx.x, g = blockIdx.y;
  int lane = threadIdx.x & 63, w = threadIdx.x >> 6;
  int wm = w >> 1, wn = w & 1;
  int q = lane >> 4, r = lane & 15;
  int mbase = 8 * bi + 4 * wm;

  f32x4 s[4][4];
#pragma unroll
  for (int mi = 0; mi < 4; ++mi)
#pragma unroll
    for (int nj = 0; nj < 4; ++nj) s[mi][nj] = (f32x4){0.f, 0.f, 0.f, 0.f};

  for (int kk = 0; kk < 16; ++kk) {
    short8 a[4], b[4];
#pragma unroll
    for (int mi = 0; mi < 4; ++mi)
      a[mi] = *reinterpret_cast<const short8*>(
          featf + ((size_t)(((mbase + mi) * 16 + kk) * 64 + lane)) * 8);
#pragma unroll
    for (int nj = 0; nj < 4; ++nj)
      b[nj] = *reinterpret_cast<const short8*>(
          w1f + ((size_t)(((g * 16 + kk) * 8 + 4 * wn + nj) * 64 + lane)) * 8);
#pragma unroll
    for (int mi = 0; mi < 4; ++mi)
#pragma unroll
      for (int nj = 0; nj < 4; ++nj)
        s[mi][nj] = __builtin_amdgcn_mfma_f32_16x16x32_bf16(a[mi], b[nj], s[mi][nj], 0, 0, 0);
  }

  const float* b1 = g == 0 ? b1_0 : g == 1 ? b1_1 : g == 2 ? b1_2 : b1_3;
#pragma unroll
  for (int nj = 0; nj < 4; ++nj) {
    int cl = 64 * wn + 16 * nj + r;
    float bias = b1[cl];
    int Cg = 128 * g + cl;
    int kkd = Cg >> 5;
    int lane2hi = ((Cg >> 3) & 3) << 4;
    int j2 = Cg & 7;
#pragma unroll
    for (int mi = 0; mi < 4; ++mi) {
#pragma unroll
      for (int v = 0; v < 4; ++v) {
        int R = 128 * bi + 64 * wm + 16 * mi + 4 * q + v;
        float val = fmaxf(s[mi][nj][v] + bias, 0.0f);
        int mb = R >> 4;
        int lane2 = lane2hi | (R & 15);
        hfrag[((size_t)((mb * 16 + kkd) * 64 + lane2)) * 8 + j2] = f2bf(val);
      }
    }
  }
}

// --------------------- stage A2: lat_g = H_g@W2_g + b2 -----------------------
__global__ __launch_bounds__(256) void k_gemm2(
    const unsigned short* __restrict__ hfrag, const unsigned short* __restrict__ w2f,
    const float* __restrict__ b2_0, const float* __restrict__ b2_1,
    const float* __restrict__ b2_2, const float* __restrict__ b2_3,
    unsigned short* __restrict__ latf) {
  int bi = blockIdx.x, g = blockIdx.y;
  int lane = threadIdx.x & 63, w = threadIdx.x >> 6;
  int wm = w >> 1, wn = w & 1;
  int q = lane >> 4, r = lane & 15;
  int mbase = 8 * bi + 4 * wm;

  f32x4 s[4][4];
#pragma unroll
  for (int mi = 0; mi < 4; ++mi)
#pragma unroll
    for (int nj = 0; nj < 4; ++nj) s[mi][nj] = (f32x4){0.f, 0.f, 0.f, 0.f};

#pragma unroll
  for (int kk = 0; kk < 4; ++kk) {
    short8 a[4], b[4];
#pragma unroll
    for (int mi = 0; mi < 4; ++mi)
      a[mi] = *reinterpret_cast<const short8*>(
          hfrag + ((size_t)(((mbase + mi) * 16 + 4 * g + kk) * 64 + lane)) * 8);
#pragma unroll
    for (int nj = 0; nj < 4; ++nj)
      b[nj] = *reinterpret_cast<const short8*>(
          w2f + ((size_t)(((g * 4 + kk) * 8 + 4 * wn + nj) * 64 + lane)) * 8);
#pragma unroll
    for (int mi = 0; mi < 4; ++mi)
#pragma unroll
      for (int nj = 0; nj < 4; ++nj)
        s[mi][nj] = __builtin_amdgcn_mfma_f32_16x16x32_bf16(a[mi], b[nj], s[mi][nj], 0, 0, 0);
  }

  const float* b2 = g == 0 ? b2_0 : g == 1 ? b2_1 : g == 2 ? b2_2 : b2_3;
#pragma unroll
  for (int nj = 0; nj < 4; ++nj) {
    int cl = 64 * wn + 16 * nj + r;
    float bias = b2[cl];
    int kkd = cl >> 5;
    int lane2hi = ((cl >> 3) & 3) << 4;
    int j2 = cl & 7;
#pragma unroll
    for (int mi = 0; mi < 4; ++mi) {
#pragma unroll
      for (int v = 0; v < 4; ++v) {
        int R = 128 * bi + 64 * wm + 16 * mi + 4 * q + v;
        float val = s[mi][nj][v] + bias;
        int mb = R >> 4;
        int lane2 = lane2hi | (R & 15);
        latf[((size_t)(((g * 512 + mb) * 4 + kkd) * 64 + lane2)) * 8 + j2] = f2bf(val);
      }
    }
  }
}

// --------------------------- stage B: fused context --------------------------
// Row-strip sweeper. Wave owns rows [16*mb_i, 16*mb_i+16), sweeps 128 16-col
// tiles. s = sum_kk mfma(fj, fi) = Lj*Li^T: lane l=16q+r, reg v holds
// out(row = 16*mb_i + r, col = 16*mb_j + 4q + v) -> float4 ew IO per step.
__global__ __launch_bounds__(256, 2) void k_ctx(
    const unsigned short* __restrict__ latf,
    const float* __restrict__ adj, const float* __restrict__ aa,
    const float* __restrict__ mod, const float* __restrict__ wsv,
    float* __restrict__ out) {
  int lane = threadIdx.x & 63, wave = threadIdx.x >> 6;
  int q = lane >> 4, r = lane & 15;

  // 512 blocks = 128 rowgroups x 4 colstrips. colstrip = bid & 3 so that
  // default round-robin XCD placement (bid % 8) gives each XCD ONE colstrip
  // -> that strip's fj panel (2MB) stays L2-resident.
  int bid = blockIdx.x;
  int rowgrp = bid >> 2;        // 0..127
  int colstrip = bid & 3;       // 0..3

  int mb_i = rowgrp * 4 + wave; // 16-row block index, 0..511
  int R = mb_i * 16 + r;        // global output row for this lane

  // softmax(ws)
  float s0w = wsv[0], s1w = wsv[1], s2w = wsv[2];
  float mx = fmaxf(fmaxf(s0w, s1w), s2w);
  float e0 = __builtin_amdgcn_exp2f(1.4426950408889634f * (s0w - mx));
  float e1 = __builtin_amdgcn_exp2f(1.4426950408889634f * (s1w - mx));
  float e2 = __builtin_amdgcn_exp2f(1.4426950408889634f * (s2w - mx));
  float inv = __builtin_amdgcn_rcpf(e0 + e1 + e2);
  float w0 = e0 * inv, w1 = e1 * inv, w2 = e2 * inv;

  // A-fragments for all 4 latents: loaded once, live for the whole sweep.
  short8 fi[4][4];
#pragma unroll
  for (int g = 0; g < 4; ++g)
#pragma unroll
    for (int kk = 0; kk < 4; ++kk)
      fi[g][kk] = *reinterpret_cast<const short8*>(
          latf + (((size_t)((g * 512 + mb_i) * 4 + kk)) << 9) + lane * 8);

  // elementwise lane offset: (row R, col colstrip*2048 + 4q), advancing 16/step
  size_t ewoff = (size_t)R * 8192 + colstrip * 2048 + 4 * q;

#pragma unroll 2
  for (int t = 0; t < 128; ++t) {
    int mb_j = colstrip * 128 + t;

    // ew loads (HBM, streaming -> nontemporal, keep L2 for fj panels)
    f32x4 ewa = __builtin_nontemporal_load(
        reinterpret_cast<const f32x4*>(aa + ewoff));
    f32x4 ewm = __builtin_nontemporal_load(
        reinterpret_cast<const f32x4*>(mod + ewoff));
    f32x4 ewj = __builtin_nontemporal_load(
        reinterpret_cast<const f32x4*>(adj + ewoff));

    // 4 grams for this 16x16 tile
    f32x4 sg[4];
#pragma unroll
    for (int g = 0; g < 4; ++g) {
      f32x4 acc = (f32x4){0.f, 0.f, 0.f, 0.f};
#pragma unroll
      for (int kk = 0; kk < 4; ++kk) {
        short8 fj = *reinterpret_cast<const short8*>(
            latf + (((size_t)((g * 512 + mb_j) * 4 + kk)) << 9) + lane * 8);
        acc = __builtin_amdgcn_mfma_f32_16x16x32_bf16(fj, fi[g][kk], acc, 0, 0, 0);
      }
      sg[g] = acc;
    }

    // combine + store
    f32x4 res;
#pragma unroll
    for (int v = 0; v < 4; ++v) {
      float o = w0 * sigf(sg[0][v])
              + w1 * sigf(sg[1][v] * ewa[v])
              + w2 * sigf(sg[2][v] * ewm[v]);
      float u = sigf(sg[3][v]);
      res[v] = ewj[v] * (o - u) + u;
    }
    __builtin_nontemporal_store(res, reinterpret_cast<f32x4*>(out + ewoff));

    ewoff += 16;
  }
}

// ------------------------------------------------------------------------------
extern "C" void kernel_launch(void* const* d_in, const int* in_sizes, int n_in,
                              void* d_out, int out_size, void* d_ws, size_t ws_size,
                              hipStream_t stream) {
  const float* feat = (const float*)d_in[0];
  const float* adj  = (const float*)d_in[1];
  const float* aa   = (const float*)d_in[2];
  const float* mod  = (const float*)d_in[3];
  // g order: 0=link, 1=aa, 2=mod, 3=unlink
  const float* W1g[4] = {(const float*)d_in[4], (const float*)d_in[12],
                         (const float*)d_in[16], (const float*)d_in[8]};
  const float* b1g[4] = {(const float*)d_in[5], (const float*)d_in[13],
                         (const float*)d_in[17], (const float*)d_in[9]};
  const float* W2g[4] = {(const float*)d_in[6], (const float*)d_in[14],
                         (const float*)d_in[18], (const float*)d_in[10]};
  const float* b2g[4] = {(const float*)d_in[7], (const float*)d_in[15],
                         (const float*)d_in[19], (const float*)d_in[11]};
  const float* wsv = (const float*)d_in[20];
  float* out = (float*)d_out;

  // workspace layout (elements of ushort)
  unsigned short* featf = (unsigned short*)d_ws;   // 4,194,304 elems (8 MiB)
  unsigned short* hfrag = featf + 4194304;         // 4,194,304
  unsigned short* latf  = hfrag + 4194304;         // 4,194,304
  unsigned short* w1f   = latf + 4194304;          //   262,144
  unsigned short* w2f   = w1f + 262144;            //    65,536
  if (ws_size < 25821184) return;

  k_featfrag<<<2048, 256, 0, stream>>>(feat, featf);
  k_wfrag<<<160, 256, 0, stream>>>(W1g[0], W1g[1], W1g[2], W1g[3],
                                   W2g[0], W2g[1], W2g[2], W2g[3], w1f, w2f);
  k_gemm1<<<dim3(64, 4), 256, 0, stream>>>(featf, w1f, b1g[0], b1g[1], b1g[2], b1g[3], hfrag);
  k_gemm2<<<dim3(64, 4), 256, 0, stream>>>(hfrag, w2f, b2g[0], b2g[1], b2g[2], b2g[3], latf);
  k_ctx<<<512, 256, 0, stream>>>(latf, adj, aa, mod, wsv, out);
}

// Round 6
// 414.962 us; speedup vs baseline: 2.2518x; 2.2518x over previous
//
#include <hip/hip_runtime.h>

// ---------------------------------------------------------------------------
// meta_model: out = (w0*sig(Ll Ll^T) + w1*sig((La La^T)*aa) + w2*sig((Lm Lm^T)*mod)
//                    - sig(Lu Lu^T)) * adj + sig(Lu Lu^T)
// with L* = mlp(feat), w = softmax(ws)
//
// R5: k_ctx staged through LDS. R1-R4 proved hipcc sinks/remats VGPR
// prefetches (VGPR_Count 64/84/124/56 across attempts) -> ew HBM latency
// always exposed. global_load_lds has NO VGPR destination, so the issue
// point is fixed where we write it:
//   - block = 128x32 out tile; aa/mod/adj tiles (3 x 16 KB) filled into LDS
//     by 12 global_load_lds/wave issued at kernel TOP; consumed after
//     gram0/1/2 respectively -> >=1 full gram phase of latency cover
//   - single __syncthreads() after gram0 (its loads are younger than the
//     fills in the vmcnt queue -> drain is nearly free)
//   - LDS linear dest + XOR-pre-swizzled GLOBAL source + XOR'd ds_read
//     (rule 21) -> bank-conflict-free b128 reads, global side still reads
//     full 128B row segments per 8 lanes
//   - wave = 64x16 quadrant: sg[4]+o[4] = 32 VGPR accum, frags reloaded
//     per kk (nothing for the allocator to sink)
//   - 16384 blocks, XCD-bijective swizzle: each XCD sweeps bj with 8
//     resident bi-panels -> latf window ~3MB L2-hot
// ---------------------------------------------------------------------------

typedef __attribute__((ext_vector_type(8))) short short8;
typedef __attribute__((ext_vector_type(4))) float f32x4;

__device__ __forceinline__ unsigned short f2bf(float x) {
  union { float f; unsigned u; } v; v.f = x;
  unsigned u = v.u + 0x7FFFu + ((v.u >> 16) & 1u);   // round-to-nearest-even
  return (unsigned short)(u >> 16);
}

__device__ __forceinline__ float sigf(float x) {
  float e = __builtin_amdgcn_exp2f(-1.4426950408889634f * x);
  return __builtin_amdgcn_rcpf(1.0f + e);
}

__device__ __forceinline__ void gload_lds16(const float* g, float* l) {
  __builtin_amdgcn_global_load_lds(
      (const __attribute__((address_space(1))) void*)g,
      (__attribute__((address_space(3))) void*)l, 16, 0, 0);
}

// --------------------------- stage A0: feat -> frag -------------------------
__global__ __launch_bounds__(256) void k_featfrag(const float* __restrict__ feat,
                                                  unsigned short* __restrict__ dst) {
  int t = blockIdx.x * 256 + threadIdx.x;   // 8192 rows * 64 chunks
  int row = t >> 6, kc = t & 63;            // 8 cols per thread
  const float4* s = reinterpret_cast<const float4*>(feat + row * 512 + kc * 8);
  float4 v0 = s[0], v1 = s[1];
  short8 o;
  o[0] = f2bf(v0.x); o[1] = f2bf(v0.y); o[2] = f2bf(v0.z); o[3] = f2bf(v0.w);
  o[4] = f2bf(v1.x); o[5] = f2bf(v1.y); o[6] = f2bf(v1.z); o[7] = f2bf(v1.w);
  int mb = row >> 4, kk = kc >> 2;
  int lane = ((kc & 3) << 4) | (row & 15);
  *reinterpret_cast<short8*>(dst + ((size_t)((mb * 16 + kk) * 64 + lane)) * 8) = o;
}

// --------------------- stage A0w: W1/W2 -> B-frag layout ---------------------
__global__ __launch_bounds__(256) void k_wfrag(
    const float* __restrict__ w1_0, const float* __restrict__ w1_1,
    const float* __restrict__ w1_2, const float* __restrict__ w1_3,
    const float* __restrict__ w2_0, const float* __restrict__ w2_1,
    const float* __restrict__ w2_2, const float* __restrict__ w2_3,
    unsigned short* __restrict__ w1f, unsigned short* __restrict__ w2f) {
  int t = blockIdx.x * 256 + threadIdx.x;
  if (t < 32768) {  // W1frag: [g][kk=16][nb=8][lane=64][j=8]
    int lane = t & 63, nb = (t >> 6) & 7, kk = (t >> 9) & 15, g = t >> 13;
    const float* W = g == 0 ? w1_0 : g == 1 ? w1_1 : g == 2 ? w1_2 : w1_3;
    int q = lane >> 4, r = lane & 15;
    int col = nb * 16 + r;
    short8 o;
#pragma unroll
    for (int j = 0; j < 8; ++j) o[j] = f2bf(W[(kk * 32 + q * 8 + j) * 128 + col]);
    *reinterpret_cast<short8*>(w1f + (size_t)t * 8) = o;
  } else if (t < 40960) {  // W2frag: [g][kk=4][nb=8][lane=64][j=8]
    int t2 = t - 32768;
    int lane = t2 & 63, nb = (t2 >> 6) & 7, kk = (t2 >> 9) & 3, g = t2 >> 11;
    const float* W = g == 0 ? w2_0 : g == 1 ? w2_1 : g == 2 ? w2_2 : w2_3;
    int q = lane >> 4, r = lane & 15;
    int col = nb * 16 + r;
    short8 o;
#pragma unroll
    for (int j = 0; j < 8; ++j) o[j] = f2bf(W[(kk * 32 + q * 8 + j) * 128 + col]);
    *reinterpret_cast<short8*>(w2f + (size_t)t2 * 8) = o;
  }
}

// --------------------- stage A1: H = relu(feat@W1cat + b1) -------------------
__global__ __launch_bounds__(256) void k_gemm1(
    const unsigned short* __restrict__ featf, const unsigned short* __restrict__ w1f,
    const float* __restrict__ b1_0, const float* __restrict__ b1_1,
    const float* __restrict__ b1_2, const float* __restrict__ b1_3,
    unsigned short* __restrict__ hfrag) {
  int bi = blockIdx.x, g = blockIdx.y;
  int lane = threadIdx.x & 63, w = threadIdx.x >> 6;
  int wm = w >> 1, wn = w & 1;
  int q = lane >> 4, r = lane & 15;
  int mbase = 8 * bi + 4 * wm;

  f32x4 s[4][4];
#pragma unroll
  for (int mi = 0; mi < 4; ++mi)
#pragma unroll
    for (int nj = 0; nj < 4; ++nj) s[mi][nj] = (f32x4){0.f, 0.f, 0.f, 0.f};

  for (int kk = 0; kk < 16; ++kk) {
    short8 a[4], b[4];
#pragma unroll
    for (int mi = 0; mi < 4; ++mi)
      a[mi] = *reinterpret_cast<const short8*>(
          featf + ((size_t)(((mbase + mi) * 16 + kk) * 64 + lane)) * 8);
#pragma unroll
    for (int nj = 0; nj < 4; ++nj)
      b[nj] = *reinterpret_cast<const short8*>(
          w1f + ((size_t)(((g * 16 + kk) * 8 + 4 * wn + nj) * 64 + lane)) * 8);
#pragma unroll
    for (int mi = 0; mi < 4; ++mi)
#pragma unroll
      for (int nj = 0; nj < 4; ++nj)
        s[mi][nj] = __builtin_amdgcn_mfma_f32_16x16x32_bf16(a[mi], b[nj], s[mi][nj], 0, 0, 0);
  }

  const float* b1 = g == 0 ? b1_0 : g == 1 ? b1_1 : g == 2 ? b1_2 : b1_3;
#pragma unroll
  for (int nj = 0; nj < 4; ++nj) {
    int cl = 64 * wn + 16 * nj + r;
    float bias = b1[cl];
    int Cg = 128 * g + cl;
    int kkd = Cg >> 5;
    int lane2hi = ((Cg >> 3) & 3) << 4;
    int j2 = Cg & 7;
#pragma unroll
    for (int mi = 0; mi < 4; ++mi) {
#pragma unroll
      for (int v = 0; v < 4; ++v) {
        int R = 128 * bi + 64 * wm + 16 * mi + 4 * q + v;
        float val = fmaxf(s[mi][nj][v] + bias, 0.0f);
        int mb = R >> 4;
        int lane2 = lane2hi | (R & 15);
        hfrag[((size_t)((mb * 16 + kkd) * 64 + lane2)) * 8 + j2] = f2bf(val);
      }
    }
  }
}

// --------------------- stage A2: lat_g = H_g@W2_g + b2 -----------------------
__global__ __launch_bounds__(256) void k_gemm2(
    const unsigned short* __restrict__ hfrag, const unsigned short* __restrict__ w2f,
    const float* __restrict__ b2_0, const float* __restrict__ b2_1,
    const float* __restrict__ b2_2, const float* __restrict__ b2_3,
    unsigned short* __restrict__ latf) {
  int bi = blockIdx.x, g = blockIdx.y;
  int lane = threadIdx.x & 63, w = threadIdx.x >> 6;
  int wm = w >> 1, wn = w & 1;
  int q = lane >> 4, r = lane & 15;
  int mbase = 8 * bi + 4 * wm;

  f32x4 s[4][4];
#pragma unroll
  for (int mi = 0; mi < 4; ++mi)
#pragma unroll
    for (int nj = 0; nj < 4; ++nj) s[mi][nj] = (f32x4){0.f, 0.f, 0.f, 0.f};

#pragma unroll
  for (int kk = 0; kk < 4; ++kk) {
    short8 a[4], b[4];
#pragma unroll
    for (int mi = 0; mi < 4; ++mi)
      a[mi] = *reinterpret_cast<const short8*>(
          hfrag + ((size_t)(((mbase + mi) * 16 + 4 * g + kk) * 64 + lane)) * 8);
#pragma unroll
    for (int nj = 0; nj < 4; ++nj)
      b[nj] = *reinterpret_cast<const short8*>(
          w2f + ((size_t)(((g * 4 + kk) * 8 + 4 * wn + nj) * 64 + lane)) * 8);
#pragma unroll
    for (int mi = 0; mi < 4; ++mi)
#pragma unroll
      for (int nj = 0; nj < 4; ++nj)
        s[mi][nj] = __builtin_amdgcn_mfma_f32_16x16x32_bf16(a[mi], b[nj], s[mi][nj], 0, 0, 0);
  }

  const float* b2 = g == 0 ? b2_0 : g == 1 ? b2_1 : g == 2 ? b2_2 : b2_3;
#pragma unroll
  for (int nj = 0; nj < 4; ++nj) {
    int cl = 64 * wn + 16 * nj + r;
    float bias = b2[cl];
    int kkd = cl >> 5;
    int lane2hi = ((cl >> 3) & 3) << 4;
    int j2 = cl & 7;
#pragma unroll
    for (int mi = 0; mi < 4; ++mi) {
#pragma unroll
      for (int v = 0; v < 4; ++v) {
        int R = 128 * bi + 64 * wm + 16 * mi + 4 * q + v;
        float val = s[mi][nj][v] + bias;
        int mb = R >> 4;
        int lane2 = lane2hi | (R & 15);
        latf[((size_t)(((g * 512 + mb) * 4 + kkd) * 64 + lane2)) * 8 + j2] = f2bf(val);
      }
    }
  }
}

// --------------------------- stage B: fused context --------------------------
// Block = 128x32 out tile. Waves 2x2; wave quadrant 64x16 (mi=0..3 16-row
// blocks x 1 16-col block). Transposed gram s=mfma(fj,fi): lane(q,r) reg v
// holds out(row=16mi+r, col=16wn+4q+v) within the tile.
// LDS: aa|mod|adj tiles [128 rows][8 quads][4 f32], quad XOR-swizzled by
// row&7 on the GLOBAL source (linear LDS dest), un-swizzled on ds_read.
__global__ __launch_bounds__(256, 3) void k_ctx(
    const unsigned short* __restrict__ latf,
    const float* __restrict__ adj, const float* __restrict__ aa,
    const float* __restrict__ mod, const float* __restrict__ wsv,
    float* __restrict__ out) {
  __shared__ float smem[3 * 4096];   // 48 KB

  // 16384 blocks = 64 bi x 256 bj; XCD-bijective swizzle (16384 % 8 == 0):
  // XCD x owns bi in [8x, 8x+8), sweeping bj fast -> ~3MB L2 window.
  int bid = blockIdx.x;
  int swz = (bid & 7) * 2048 + (bid >> 3);
  int bi = swz >> 8;        // 0..63   (128-row panel)
  int bj = swz & 255;       // 0..255  (32-col strip)

  int tid = threadIdx.x;
  int lane = tid & 63, w = tid >> 6;
  int q = lane >> 4, r = lane & 15;
  int wm = w >> 1, wn = w & 1;

  // ---- issue ALL ew tile fills first (no VGPR dest -> cannot be sunk) ----
  // wave w fills tile rows [32w, 32w+32): 4 chunks x 1KB per matrix.
  // lane l: row R = 32w+8c+(l>>3); writes physical quad p=l&7 at LDS
  // base+l*16; global source = logical quad j = p ^ (R&7)  (pre-swizzle).
  {
    int lrow = lane >> 3;
    int lq = lane & 7;
    int jq = lq ^ (lrow & 7);   // R&7 == lrow&7 since 32w+8c = 0 (mod 8)
#pragma unroll
    for (int c = 0; c < 4; ++c) {
      size_t grow = (size_t)(128 * bi + 32 * w + 8 * c + lrow);
      size_t goff = grow * 8192 + bj * 32 + jq * 4;
      float* lbase = &smem[(32 * w + 8 * c) * 32];   // wave-uniform
      gload_lds16(aa + goff, lbase);
      gload_lds16(mod + goff, lbase + 4096);
      gload_lds16(adj + goff, lbase + 8192);
    }
  }

  // softmax(ws)
  float s0w = wsv[0], s1w = wsv[1], s2w = wsv[2];
  float mx = fmaxf(fmaxf(s0w, s1w), s2w);
  float e0 = __builtin_amdgcn_exp2f(1.4426950408889634f * (s0w - mx));
  float e1 = __builtin_amdgcn_exp2f(1.4426950408889634f * (s1w - mx));
  float e2 = __builtin_amdgcn_exp2f(1.4426950408889634f * (s2w - mx));
  float inv = __builtin_amdgcn_rcpf(e0 + e1 + e2);
  float w0 = e0 * inv, w1 = e1 * inv, w2 = e2 * inv;

  const size_t GS = (size_t)512 * 4 * 64 * 8;   // latf elems per latent
  int mbi0 = bi * 8 + wm * 4;                   // row 16-block base (+mi)
  int mbj = bj * 2 + wn;                        // col 16-block

  // ds_read index helper pieces (conflict-free: floor-only on b128)
  int physq = (4 * wn + q) ^ (r & 7);
  int ldsrow0 = 64 * wm + r;                    // + 16*mi

  f32x4 sg[4], o[4];

  // ---------------- g = 0: link (no elementwise input) ----------------
  {
    const unsigned short* Lg = latf + 0 * GS;
#pragma unroll
    for (int mi = 0; mi < 4; ++mi) sg[mi] = (f32x4){0.f, 0.f, 0.f, 0.f};
#pragma unroll
    for (int kk = 0; kk < 4; ++kk) {
      short8 fj = *reinterpret_cast<const short8*>(
          Lg + (((size_t)mbj * 4 + kk) << 9) + lane * 8);
#pragma unroll
      for (int mi = 0; mi < 4; ++mi) {
        short8 fi = *reinterpret_cast<const short8*>(
            Lg + (((size_t)(mbi0 + mi) * 4 + kk) << 9) + lane * 8);
        sg[mi] = __builtin_amdgcn_mfma_f32_16x16x32_bf16(fj, fi, sg[mi], 0, 0, 0);
      }
    }
#pragma unroll
    for (int mi = 0; mi < 4; ++mi)
#pragma unroll
      for (int v = 0; v < 4; ++v)
        o[mi][v] = w0 * sigf(sg[mi][v]);
  }

  // LDS fills complete: gram0's loads are younger in the vmcnt queue, so
  // the implied vmcnt(0) here is ~free; barrier covers cross-wave writes.
  __syncthreads();

  // ---------------- g = 1: aa ----------------
  {
    const unsigned short* Lg = latf + 1 * GS;
#pragma unroll
    for (int mi = 0; mi < 4; ++mi) sg[mi] = (f32x4){0.f, 0.f, 0.f, 0.f};
#pragma unroll
    for (int kk = 0; kk < 4; ++kk) {
      short8 fj = *reinterpret_cast<const short8*>(
          Lg + (((size_t)mbj * 4 + kk) << 9) + lane * 8);
#pragma unroll
      for (int mi = 0; mi < 4; ++mi) {
        short8 fi = *reinterpret_cast<const short8*>(
            Lg + (((size_t)(mbi0 + mi) * 4 + kk) << 9) + lane * 8);
        sg[mi] = __builtin_amdgcn_mfma_f32_16x16x32_bf16(fj, fi, sg[mi], 0, 0, 0);
      }
    }
#pragma unroll
    for (int mi = 0; mi < 4; ++mi) {
      f32x4 ew = *reinterpret_cast<const f32x4*>(
          &smem[(ldsrow0 + 16 * mi) * 32 + physq * 4]);
#pragma unroll
      for (int v = 0; v < 4; ++v)
        o[mi][v] += w1 * sigf(sg[mi][v] * ew[v]);
    }
  }

  // ---------------- g = 2: mod ----------------
  {
    const unsigned short* Lg = latf + 2 * GS;
#pragma unroll
    for (int mi = 0; mi < 4; ++mi) sg[mi] = (f32x4){0.f, 0.f, 0.f, 0.f};
#pragma unroll
    for (int kk = 0; kk < 4; ++kk) {
      short8 fj = *reinterpret_cast<const short8*>(
          Lg + (((size_t)mbj * 4 + kk) << 9) + lane * 8);
#pragma unroll
      for (int mi = 0; mi < 4; ++mi) {
        short8 fi = *reinterpret_cast<const short8*>(
            Lg + (((size_t)(mbi0 + mi) * 4 + kk) << 9) + lane * 8);
        sg[mi] = __builtin_amdgcn_mfma_f32_16x16x32_bf16(fj, fi, sg[mi], 0, 0, 0);
      }
    }
#pragma unroll
    for (int mi = 0; mi < 4; ++mi) {
      f32x4 ew = *reinterpret_cast<const f32x4*>(
          &smem[4096 + (ldsrow0 + 16 * mi) * 32 + physq * 4]);
#pragma unroll
      for (int v = 0; v < 4; ++v)
        o[mi][v] += w2 * sigf(sg[mi][v] * ew[v]);
    }
  }

  // ---------------- g = 3: unlink + combine + store ----------------
  {
    const unsigned short* Lg = latf + 3 * GS;
#pragma unroll
    for (int mi = 0; mi < 4; ++mi) sg[mi] = (f32x4){0.f, 0.f, 0.f, 0.f};
#pragma unroll
    for (int kk = 0; kk < 4; ++kk) {
      short8 fj = *reinterpret_cast<const short8*>(
          Lg + (((size_t)mbj * 4 + kk) << 9) + lane * 8);
#pragma unroll
      for (int mi = 0; mi < 4; ++mi) {
        short8 fi = *reinterpret_cast<const short8*>(
            Lg + (((size_t)(mbi0 + mi) * 4 + kk) << 9) + lane * 8);
        sg[mi] = __builtin_amdgcn_mfma_f32_16x16x32_bf16(fj, fi, sg[mi], 0, 0, 0);
      }
    }
#pragma unroll
    for (int mi = 0; mi < 4; ++mi) {
      f32x4 ew = *reinterpret_cast<const f32x4*>(
          &smem[8192 + (ldsrow0 + 16 * mi) * 32 + physq * 4]);
      f32x4 res;
#pragma unroll
      for (int v = 0; v < 4; ++v) {
        float u = sigf(sg[mi][v]);
        res[v] = ew[v] * (o[mi][v] - u) + u;
      }
      size_t off = (size_t)(128 * bi + ldsrow0 + 16 * mi) * 8192
                 + bj * 32 + 16 * wn + 4 * q;
      __builtin_nontemporal_store(res, reinterpret_cast<f32x4*>(out + off));
    }
  }
}

// ------------------------------------------------------------------------------
extern "C" void kernel_launch(void* const* d_in, const int* in_sizes, int n_in,
                              void* d_out, int out_size, void* d_ws, size_t ws_size,
                              hipStream_t stream) {
  const float* feat = (const float*)d_in[0];
  const float* adj  = (const float*)d_in[1];
  const float* aa   = (const float*)d_in[2];
  const float* mod  = (const float*)d_in[3];
  // g order: 0=link, 1=aa, 2=mod, 3=unlink
  const float* W1g[4] = {(const float*)d_in[4], (const float*)d_in[12],
                         (const float*)d_in[16], (const float*)d_in[8]};
  const float* b1g[4] = {(const float*)d_in[5], (const float*)d_in[13],
                         (const float*)d_in[17], (const float*)d_in[9]};
  const float* W2g[4] = {(const float*)d_in[6], (const float*)d_in[14],
                         (const float*)d_in[18], (const float*)d_in[10]};
  const float* b2g[4] = {(const float*)d_in[7], (const float*)d_in[15],
                         (const float*)d_in[19], (const float*)d_in[11]};
  const float* wsv = (const float*)d_in[20];
  float* out = (float*)d_out;

  // workspace layout (elements of ushort)
  unsigned short* featf = (unsigned short*)d_ws;   // 4,194,304 elems (8 MiB)
  unsigned short* hfrag = featf + 4194304;         // 4,194,304
  unsigned short* latf  = hfrag + 4194304;         // 4,194,304
  unsigned short* w1f   = latf + 4194304;          //   262,144
  unsigned short* w2f   = w1f + 262144;            //    65,536
  if (ws_size < 25821184) return;

  k_featfrag<<<2048, 256, 0, stream>>>(feat, featf);
  k_wfrag<<<160, 256, 0, stream>>>(W1g[0], W1g[1], W1g[2], W1g[3],
                                   W2g[0], W2g[1], W2g[2], W2g[3], w1f, w2f);
  k_gemm1<<<dim3(64, 4), 256, 0, stream>>>(featf, w1f, b1g[0], b1g[1], b1g[2], b1g[3], hfrag);
  k_gemm2<<<dim3(64, 4), 256, 0, stream>>>(hfrag, w2f, b2g[0], b2g[1], b2g[2], b2g[3], latf);
  k_ctx<<<16384, 256, 0, stream>>>(latf, adj, aa, mod, wsv, out);
}

// Round 7
// 412.424 us; speedup vs baseline: 2.2657x; 1.0062x over previous
//
#include <hip/hip_runtime.h>

// ---------------------------------------------------------------------------
// meta_model: out = (w0*sig(Ll Ll^T) + w1*sig((La La^T)*aa) + w2*sig((Lm Lm^T)*mod)
//                    - sig(Lu Lu^T)) * adj + sig(Lu Lu^T)
// with L* = mlp(feat), w = softmax(ws)
//
// R6: 2-phase pipelined strip-sweeper for k_ctx.
// R5 failed because vmcnt is IN-ORDER: gram0's latf loads (younger than the
// LDS fills) forced a full fill drain before the first MFMA -> zero latency
// cover. New schedule:
//   - block = 512 thr (8 waves x 16 rows), 64 steps x 16 cols per block
//   - fi frags (4x4 = 64 VGPR) loaded ONCE, pinned via asm "+v" (anti-remat)
//   - per step, per gram g: [4 fj loads][1 LDS fill for t+1][sched_barrier]
//     [4 MFMA][sigmoid combine]  -> MFMA waits vmcnt(1), fill stays in
//     flight >= 1 gram phase; step ends with vmcnt(0)+barrier (2-phase drain)
//   - LDS dbuf 2 x 3 x 8KB = 48KB; each wave fills/reads its own lane-linear
//     1KB chunk -> conflict-free by identity, no swizzle
//   - 512 blocks = 2/CU ALL resident; colstrip = bid&7 == XCD id -> each
//     XCD's fj panel (~1MB) L2-resident; adjacent-step 128B-line halves
//     shared via L2 (plain loads/stores, no nontemporal)
// ---------------------------------------------------------------------------

typedef __attribute__((ext_vector_type(8))) short short8;
typedef __attribute__((ext_vector_type(4))) float f32x4;

__device__ __forceinline__ unsigned short f2bf(float x) {
  union { float f; unsigned u; } v; v.f = x;
  unsigned u = v.u + 0x7FFFu + ((v.u >> 16) & 1u);   // round-to-nearest-even
  return (unsigned short)(u >> 16);
}

__device__ __forceinline__ float sigf(float x) {
  float e = __builtin_amdgcn_exp2f(-1.4426950408889634f * x);
  return __builtin_amdgcn_rcpf(1.0f + e);
}

__device__ __forceinline__ void gload_lds16(const float* g, float* l) {
  __builtin_amdgcn_global_load_lds(
      (const __attribute__((address_space(1))) void*)g,
      (__attribute__((address_space(3))) void*)l, 16, 0, 0);
}

// --------------------------- stage A0: feat -> frag -------------------------
__global__ __launch_bounds__(256) void k_featfrag(const float* __restrict__ feat,
                                                  unsigned short* __restrict__ dst) {
  int t = blockIdx.x * 256 + threadIdx.x;   // 8192 rows * 64 chunks
  int row = t >> 6, kc = t & 63;            // 8 cols per thread
  const float4* s = reinterpret_cast<const float4*>(feat + row * 512 + kc * 8);
  float4 v0 = s[0], v1 = s[1];
  short8 o;
  o[0] = f2bf(v0.x); o[1] = f2bf(v0.y); o[2] = f2bf(v0.z); o[3] = f2bf(v0.w);
  o[4] = f2bf(v1.x); o[5] = f2bf(v1.y); o[6] = f2bf(v1.z); o[7] = f2bf(v1.w);
  int mb = row >> 4, kk = kc >> 2;
  int lane = ((kc & 3) << 4) | (row & 15);
  *reinterpret_cast<short8*>(dst + ((size_t)((mb * 16 + kk) * 64 + lane)) * 8) = o;
}

// --------------------- stage A0w: W1/W2 -> B-frag layout ---------------------
__global__ __launch_bounds__(256) void k_wfrag(
    const float* __restrict__ w1_0, const float* __restrict__ w1_1,
    const float* __restrict__ w1_2, const float* __restrict__ w1_3,
    const float* __restrict__ w2_0, const float* __restrict__ w2_1,
    const float* __restrict__ w2_2, const float* __restrict__ w2_3,
    unsigned short* __restrict__ w1f, unsigned short* __restrict__ w2f) {
  int t = blockIdx.x * 256 + threadIdx.x;
  if (t < 32768) {  // W1frag: [g][kk=16][nb=8][lane=64][j=8]
    int lane = t & 63, nb = (t >> 6) & 7, kk = (t >> 9) & 15, g = t >> 13;
    const float* W = g == 0 ? w1_0 : g == 1 ? w1_1 : g == 2 ? w1_2 : w1_3;
    int q = lane >> 4, r = lane & 15;
    int col = nb * 16 + r;
    short8 o;
#pragma unroll
    for (int j = 0; j < 8; ++j) o[j] = f2bf(W[(kk * 32 + q * 8 + j) * 128 + col]);
    *reinterpret_cast<short8*>(w1f + (size_t)t * 8) = o;
  } else if (t < 40960) {  // W2frag: [g][kk=4][nb=8][lane=64][j=8]
    int t2 = t - 32768;
    int lane = t2 & 63, nb = (t2 >> 6) & 7, kk = (t2 >> 9) & 3, g = t2 >> 11;
    const float* W = g == 0 ? w2_0 : g == 1 ? w2_1 : g == 2 ? w2_2 : w2_3;
    int q = lane >> 4, r = lane & 15;
    int col = nb * 16 + r;
    short8 o;
#pragma unroll
    for (int j = 0; j < 8; ++j) o[j] = f2bf(W[(kk * 32 + q * 8 + j) * 128 + col]);
    *reinterpret_cast<short8*>(w2f + (size_t)t2 * 8) = o;
  }
}

// --------------------- stage A1: H = relu(feat@W1cat + b1) -------------------
__global__ __launch_bounds__(256) void k_gemm1(
    const unsigned short* __restrict__ featf, const unsigned short* __restrict__ w1f,
    const float* __restrict__ b1_0, const float* __restrict__ b1_1,
    const float* __restrict__ b1_2, const float* __restrict__ b1_3,
    unsigned short* __restrict__ hfrag) {
  int bi = blockIdx.x, g = blockIdx.y;
  int lane = threadIdx.x & 63, w = threadIdx.x >> 6;
  int wm = w >> 1, wn = w & 1;
  int q = lane >> 4, r = lane & 15;
  int mbase = 8 * bi + 4 * wm;

  f32x4 s[4][4];
#pragma unroll
  for (int mi = 0; mi < 4; ++mi)
#pragma unroll
    for (int nj = 0; nj < 4; ++nj) s[mi][nj] = (f32x4){0.f, 0.f, 0.f, 0.f};

  for (int kk = 0; kk < 16; ++kk) {
    short8 a[4], b[4];
#pragma unroll
    for (int mi = 0; mi < 4; ++mi)
      a[mi] = *reinterpret_cast<const short8*>(
          featf + ((size_t)(((mbase + mi) * 16 + kk) * 64 + lane)) * 8);
#pragma unroll
    for (int nj = 0; nj < 4; ++nj)
      b[nj] = *reinterpret_cast<const short8*>(
          w1f + ((size_t)(((g * 16 + kk) * 8 + 4 * wn + nj) * 64 + lane)) * 8);
#pragma unroll
    for (int mi = 0; mi < 4; ++mi)
#pragma unroll
      for (int nj = 0; nj < 4; ++nj)
        s[mi][nj] = __builtin_amdgcn_mfma_f32_16x16x32_bf16(a[mi], b[nj], s[mi][nj], 0, 0, 0);
  }

  const float* b1 = g == 0 ? b1_0 : g == 1 ? b1_1 : g == 2 ? b1_2 : b1_3;
#pragma unroll
  for (int nj = 0; nj < 4; ++nj) {
    int cl = 64 * wn + 16 * nj + r;
    float bias = b1[cl];
    int Cg = 128 * g + cl;
    int kkd = Cg >> 5;
    int lane2hi = ((Cg >> 3) & 3) << 4;
    int j2 = Cg & 7;
#pragma unroll
    for (int mi = 0; mi < 4; ++mi) {
#pragma unroll
      for (int v = 0; v < 4; ++v) {
        int R = 128 * bi + 64 * wm + 16 * mi + 4 * q + v;
        float val = fmaxf(s[mi][nj][v] + bias, 0.0f);
        int mb = R >> 4;
        int lane2 = lane2hi | (R & 15);
        hfrag[((size_t)((mb * 16 + kkd) * 64 + lane2)) * 8 + j2] = f2bf(val);
      }
    }
  }
}

// --------------------- stage A2: lat_g = H_g@W2_g + b2 -----------------------
__global__ __launch_bounds__(256) void k_gemm2(
    const unsigned short* __restrict__ hfrag, const unsigned short* __restrict__ w2f,
    const float* __restrict__ b2_0, const float* __restrict__ b2_1,
    const float* __restrict__ b2_2, const float* __restrict__ b2_3,
    unsigned short* __restrict__ latf) {
  int bi = blockIdx.x, g = blockIdx.y;
  int lane = threadIdx.x & 63, w = threadIdx.x >> 6;
  int wm = w >> 1, wn = w & 1;
  int q = lane >> 4, r = lane & 15;
  int mbase = 8 * bi + 4 * wm;

  f32x4 s[4][4];
#pragma unroll
  for (int mi = 0; mi < 4; ++mi)
#pragma unroll
    for (int nj = 0; nj < 4; ++nj) s[mi][nj] = (f32x4){0.f, 0.f, 0.f, 0.f};

#pragma unroll
  for (int kk = 0; kk < 4; ++kk) {
    short8 a[4], b[4];
#pragma unroll
    for (int mi = 0; mi < 4; ++mi)
      a[mi] = *reinterpret_cast<const short8*>(
          hfrag + ((size_t)(((mbase + mi) * 16 + 4 * g + kk) * 64 + lane)) * 8);
#pragma unroll
    for (int nj = 0; nj < 4; ++nj)
      b[nj] = *reinterpret_cast<const short8*>(
          w2f + ((size_t)(((g * 4 + kk) * 8 + 4 * wn + nj) * 64 + lane)) * 8);
#pragma unroll
    for (int mi = 0; mi < 4; ++mi)
#pragma unroll
      for (int nj = 0; nj < 4; ++nj)
        s[mi][nj] = __builtin_amdgcn_mfma_f32_16x16x32_bf16(a[mi], b[nj], s[mi][nj], 0, 0, 0);
  }

  const float* b2 = g == 0 ? b2_0 : g == 1 ? b2_1 : g == 2 ? b2_2 : b2_3;
#pragma unroll
  for (int nj = 0; nj < 4; ++nj) {
    int cl = 64 * wn + 16 * nj + r;
    float bias = b2[cl];
    int kkd = cl >> 5;
    int lane2hi = ((cl >> 3) & 3) << 4;
    int j2 = cl & 7;
#pragma unroll
    for (int mi = 0; mi < 4; ++mi) {
#pragma unroll
      for (int v = 0; v < 4; ++v) {
        int R = 128 * bi + 64 * wm + 16 * mi + 4 * q + v;
        float val = s[mi][nj][v] + bias;
        int mb = R >> 4;
        int lane2 = lane2hi | (R & 15);
        latf[((size_t)(((g * 512 + mb) * 4 + kkd) * 64 + lane2)) * 8 + j2] = f2bf(val);
      }
    }
  }
}

// --------------------------- stage B: fused context --------------------------
// Block: 512 threads = 8 waves; wave owns 16 rows (mbi = rowgrp*8 + w) and
// sweeps 64 steps of 16 cols within its colstrip. s = mfma(fj, fi): lane
// (q,r), reg v -> out(row = 16*mbi + r, col = 16*mbj + 4q + v).
// LDS: smem[buf][mat][wave*256 + lane*4] holds the wave's own 16x16 f32 ew
// tile, filled lane-linear by global_load_lds and read back lane-linear.
__global__ __launch_bounds__(512, 4) void k_ctx(
    const unsigned short* __restrict__ latf,
    const float* __restrict__ adj, const float* __restrict__ aa,
    const float* __restrict__ mod, const float* __restrict__ wsv,
    float* __restrict__ out) {
  __shared__ float smem[2][3][2048];   // 48 KB: [dbuf][aa|mod|adj][8 waves*256]

  int bid = blockIdx.x;            // 512 blocks, ALL resident (2/CU)
  int colstrip = bid & 7;          // == XCD id under round-robin dispatch
  int rowgrp = bid >> 3;           // 0..63

  int tid = threadIdx.x;
  int lane = tid & 63, w = tid >> 6;
  int q = lane >> 4, r = lane & 15;

  int mbi = rowgrp * 8 + w;        // wave's 16-row block (0..511)
  int mbj0 = colstrip * 64;        // first 16-col block of the strip

  // per-lane global offset for ew tiles: (row 16*mbi + r, col 16*mbj + 4q)
  size_t ewoff = (size_t)(mbi * 16 + r) * 8192 + (size_t)mbj0 * 16 + 4 * q;

  // softmax(ws)
  float s0w = wsv[0], s1w = wsv[1], s2w = wsv[2];
  float mx = fmaxf(fmaxf(s0w, s1w), s2w);
  float e0 = __builtin_amdgcn_exp2f(1.4426950408889634f * (s0w - mx));
  float e1 = __builtin_amdgcn_exp2f(1.4426950408889634f * (s1w - mx));
  float e2 = __builtin_amdgcn_exp2f(1.4426950408889634f * (s2w - mx));
  float inv = __builtin_amdgcn_rcpf(e0 + e1 + e2);
  float w0 = e0 * inv, w1 = e1 * inv, w2 = e2 * inv;

  const size_t GS = (size_t)512 * 2048;   // latf elements per latent

  // ---- fi fragments: 4 latents x 4 kk, loaded once, pinned vs remat ----
  short8 fi[4][4];
#pragma unroll
  for (int g = 0; g < 4; ++g)
#pragma unroll
    for (int kk = 0; kk < 4; ++kk) {
      fi[g][kk] = *reinterpret_cast<const short8*>(
          latf + GS * g + (((size_t)mbi * 4 + kk) << 9) + lane * 8);
      asm volatile("" : "+v"(fi[g][kk]));
    }

  // ---- prologue: fill step-0 tiles into buf 0 ----
  gload_lds16(aa + ewoff, &smem[0][0][w * 256]);
  gload_lds16(mod + ewoff, &smem[0][1][w * 256]);
  gload_lds16(adj + ewoff, &smem[0][2][w * 256]);
  asm volatile("s_waitcnt vmcnt(0)" ::: "memory");
  __syncthreads();

  for (int t = 0; t < 64; ++t) {
    int buf = t & 1, nbuf = buf ^ 1;
    bool dofill = (t < 63);
    size_t ewnext = ewoff + (size_t)(t + 1) * 16;
    const unsigned short* fjb =
        latf + (((size_t)(mbj0 + t) * 4) << 9) + lane * 8;

    f32x4 sg, o4;

    // ---------------- g0: link ----------------
    {
      short8 fj0 = *reinterpret_cast<const short8*>(fjb + GS * 0);
      short8 fj1 = *reinterpret_cast<const short8*>(fjb + GS * 0 + 512);
      short8 fj2 = *reinterpret_cast<const short8*>(fjb + GS * 0 + 1024);
      short8 fj3 = *reinterpret_cast<const short8*>(fjb + GS * 0 + 1536);
      if (dofill) gload_lds16(aa + ewnext, &smem[nbuf][0][w * 256]);
      __builtin_amdgcn_sched_barrier(0);
      sg = (f32x4){0.f, 0.f, 0.f, 0.f};
      sg = __builtin_amdgcn_mfma_f32_16x16x32_bf16(fj0, fi[0][0], sg, 0, 0, 0);
      sg = __builtin_amdgcn_mfma_f32_16x16x32_bf16(fj1, fi[0][1], sg, 0, 0, 0);
      sg = __builtin_amdgcn_mfma_f32_16x16x32_bf16(fj2, fi[0][2], sg, 0, 0, 0);
      sg = __builtin_amdgcn_mfma_f32_16x16x32_bf16(fj3, fi[0][3], sg, 0, 0, 0);
#pragma unroll
      for (int v = 0; v < 4; ++v) o4[v] = w0 * sigf(sg[v]);
    }

    // ---------------- g1: aa ----------------
    {
      short8 fj0 = *reinterpret_cast<const short8*>(fjb + GS * 1);
      short8 fj1 = *reinterpret_cast<const short8*>(fjb + GS * 1 + 512);
      short8 fj2 = *reinterpret_cast<const short8*>(fjb + GS * 1 + 1024);
      short8 fj3 = *reinterpret_cast<const short8*>(fjb + GS * 1 + 1536);
      if (dofill) gload_lds16(mod + ewnext, &smem[nbuf][1][w * 256]);
      __builtin_amdgcn_sched_barrier(0);
      sg = (f32x4){0.f, 0.f, 0.f, 0.f};
      sg = __builtin_amdgcn_mfma_f32_16x16x32_bf16(fj0, fi[1][0], sg, 0, 0, 0);
      sg = __builtin_amdgcn_mfma_f32_16x16x32_bf16(fj1, fi[1][1], sg, 0, 0, 0);
      sg = __builtin_amdgcn_mfma_f32_16x16x32_bf16(fj2, fi[1][2], sg, 0, 0, 0);
      sg = __builtin_amdgcn_mfma_f32_16x16x32_bf16(fj3, fi[1][3], sg, 0, 0, 0);
      f32x4 ew = *reinterpret_cast<const f32x4*>(&smem[buf][0][w * 256 + lane * 4]);
#pragma unroll
      for (int v = 0; v < 4; ++v) o4[v] += w1 * sigf(sg[v] * ew[v]);
    }

    // ---------------- g2: mod ----------------
    {
      short8 fj0 = *reinterpret_cast<const short8*>(fjb + GS * 2);
      short8 fj1 = *reinterpret_cast<const short8*>(fjb + GS * 2 + 512);
      short8 fj2 = *reinterpret_cast<const short8*>(fjb + GS * 2 + 1024);
      short8 fj3 = *reinterpret_cast<const short8*>(fjb + GS * 2 + 1536);
      if (dofill) gload_lds16(adj + ewnext, &smem[nbuf][2][w * 256]);
      __builtin_amdgcn_sched_barrier(0);
      sg = (f32x4){0.f, 0.f, 0.f, 0.f};
      sg = __builtin_amdgcn_mfma_f32_16x16x32_bf16(fj0, fi[2][0], sg, 0, 0, 0);
      sg = __builtin_amdgcn_mfma_f32_16x16x32_bf16(fj1, fi[2][1], sg, 0, 0, 0);
      sg = __builtin_amdgcn_mfma_f32_16x16x32_bf16(fj2, fi[2][2], sg, 0, 0, 0);
      sg = __builtin_amdgcn_mfma_f32_16x16x32_bf16(fj3, fi[2][3], sg, 0, 0, 0);
      f32x4 ew = *reinterpret_cast<const f32x4*>(&smem[buf][1][w * 256 + lane * 4]);
#pragma unroll
      for (int v = 0; v < 4; ++v) o4[v] += w2 * sigf(sg[v] * ew[v]);
    }

    // ---------------- g3: unlink + combine + store ----------------
    {
      short8 fj0 = *reinterpret_cast<const short8*>(fjb + GS * 3);
      short8 fj1 = *reinterpret_cast<const short8*>(fjb + GS * 3 + 512);
      short8 fj2 = *reinterpret_cast<const short8*>(fjb + GS * 3 + 1024);
      short8 fj3 = *reinterpret_cast<const short8*>(fjb + GS * 3 + 1536);
      sg = (f32x4){0.f, 0.f, 0.f, 0.f};
      sg = __builtin_amdgcn_mfma_f32_16x16x32_bf16(fj0, fi[3][0], sg, 0, 0, 0);
      sg = __builtin_amdgcn_mfma_f32_16x16x32_bf16(fj1, fi[3][1], sg, 0, 0, 0);
      sg = __builtin_amdgcn_mfma_f32_16x16x32_bf16(fj2, fi[3][2], sg, 0, 0, 0);
      sg = __builtin_amdgcn_mfma_f32_16x16x32_bf16(fj3, fi[3][3], sg, 0, 0, 0);
      f32x4 ew = *reinterpret_cast<const f32x4*>(&smem[buf][2][w * 256 + lane * 4]);
      f32x4 res;
#pragma unroll
      for (int v = 0; v < 4; ++v) {
        float u = sigf(sg[v]);
        res[v] = ew[v] * (o4[v] - u) + u;
      }
      *reinterpret_cast<f32x4*>(out + ewoff + (size_t)t * 16) = res;
    }

    // step end: drain this step's fills (2-phase), swap buffers
    asm volatile("s_waitcnt vmcnt(0)" ::: "memory");
    __syncthreads();
  }
}

// ------------------------------------------------------------------------------
extern "C" void kernel_launch(void* const* d_in, const int* in_sizes, int n_in,
                              void* d_out, int out_size, void* d_ws, size_t ws_size,
                              hipStream_t stream) {
  const float* feat = (const float*)d_in[0];
  const float* adj  = (const float*)d_in[1];
  const float* aa   = (const float*)d_in[2];
  const float* mod  = (const float*)d_in[3];
  // g order: 0=link, 1=aa, 2=mod, 3=unlink
  const float* W1g[4] = {(const float*)d_in[4], (const float*)d_in[12],
                         (const float*)d_in[16], (const float*)d_in[8]};
  const float* b1g[4] = {(const float*)d_in[5], (const float*)d_in[13],
                         (const float*)d_in[17], (const float*)d_in[9]};
  const float* W2g[4] = {(const float*)d_in[6], (const float*)d_in[14],
                         (const float*)d_in[18], (const float*)d_in[10]};
  const float* b2g[4] = {(const float*)d_in[7], (const float*)d_in[15],
                         (const float*)d_in[19], (const float*)d_in[11]};
  const float* wsv = (const float*)d_in[20];
  float* out = (float*)d_out;

  // workspace layout (elements of ushort)
  unsigned short* featf = (unsigned short*)d_ws;   // 4,194,304 elems (8 MiB)
  unsigned short* hfrag = featf + 4194304;         // 4,194,304
  unsigned short* latf  = hfrag + 4194304;         // 4,194,304
  unsigned short* w1f   = latf + 4194304;          //   262,144
  unsigned short* w2f   = w1f + 262144;            //    65,536
  if (ws_size < 25821184) return;

  k_featfrag<<<2048, 256, 0, stream>>>(feat, featf);
  k_wfrag<<<160, 256, 0, stream>>>(W1g[0], W1g[1], W1g[2], W1g[3],
                                   W2g[0], W2g[1], W2g[2], W2g[3], w1f, w2f);
  k_gemm1<<<dim3(64, 4), 256, 0, stream>>>(featf, w1f, b1g[0], b1g[1], b1g[2], b1g[3], hfrag);
  k_gemm2<<<dim3(64, 4), 256, 0, stream>>>(hfrag, w2f, b2g[0], b2g[1], b2g[2], b2g[3], latf);
  k_ctx<<<512, 512, 0, stream>>>(latf, adj, aa, mod, wsv, out);
}